// Round 3
// baseline (16193.951 us; speedup 1.0000x reference)
//
#include <hip/hip_runtime.h>
#include <hip/hip_bf16.h>
#include <stdint.h>

#define HH 1024
#define BB 64
#define TT 1024

typedef __attribute__((ext_vector_type(8))) short short8;
typedef __attribute__((ext_vector_type(4))) float f32x4;

__device__ __forceinline__ unsigned short f2bf(float f) {
  union { float f; unsigned u; } v; v.f = f;
  unsigned r = v.u + 0x7fffu + ((v.u >> 16) & 1u);
  return (unsigned short)(r >> 16);
}

__device__ __forceinline__ float h2f(unsigned short u) {
  _Float16 h;
  __builtin_memcpy(&h, &u, 2);
  return (float)h;
}

// tanh(x) = 1 - 2/(exp(2x)+1); v_exp + v_rcp, ~1e-6 abs error, exact at 0, +-1 at inf.
__device__ __forceinline__ float ftanh(float x) {
  float e = __expf(2.0f * x);
  return 1.0f - 2.0f * __builtin_amdgcn_rcpf(e + 1.0f);
}

// Convert weights to bf16 (RNE) and fold the two biases together.
__global__ void prep_kernel(const float* __restrict__ Wih, const float* __restrict__ Whh,
                            const float* __restrict__ bih, const float* __restrict__ bhh,
                            unsigned short* __restrict__ wih_b, unsigned short* __restrict__ whh_b,
                            float* __restrict__ bias01) {
  int i = blockIdx.x * 256 + threadIdx.x;   // grid sized exactly 2*H*H
  wih_b[i] = f2bf(Wih[i]);
  whh_b[i] = f2bf(Whh[i]);
  if (i < 2 * HH) bias01[i] = bih[i] + bhh[i];
}

// Row permutation between [b][t] and [t][b] orderings (B=64, T=1024, M=65536).
__device__ __forceinline__ size_t rowperm(int r) {
  return ((size_t)(r & 63) << 10) | (size_t)(r >> 6);
}

// Bulk GEMM: Gout[crow(r), n] = sum_k A[arow(r),k] * W[n,k] + bias[n].
// M = 65536, N = K = 1024. 128x128 tile, BK=32, 4 waves x 64x64.
// OUTF16: store result as fp16 (ushort) instead of fp32.
template<bool ABF16, bool APERM, bool CPERM, bool OUTF16>
__global__ __launch_bounds__(256)
void gemm_bias(const void* __restrict__ Av, const unsigned short* __restrict__ Wb,
               const float* __restrict__ bias, void* __restrict__ GoutV) {
  __shared__ unsigned short As[128 * 40];
  __shared__ unsigned short Bs[128 * 40];
  const int tn = blockIdx.x & 7;
  const int tm = blockIdx.x >> 3;
  const int tid = threadIdx.x;
  const int wid = tid >> 6, lane = tid & 63;
  const int wr = (wid >> 1) * 64, wc = (wid & 1) * 64;
  const int l15 = lane & 15, l4 = lane >> 4;
  f32x4 acc[4][4] = {};

  const float* Af = (const float*)Av;
  const unsigned short* Ab = (const unsigned short*)Av;
  const int sr = tid >> 2;
  const int sk = (tid & 3) * 8;

  for (int k0 = 0; k0 < HH; k0 += 32) {
    __syncthreads();
#pragma unroll
    for (int p = 0; p < 2; ++p) {
      const int row = p * 64 + sr;
      const int rg = tm * 128 + row;
      const size_t ar = APERM ? rowperm(rg) : (size_t)rg;
      if (ABF16) {
        const unsigned short* src = Ab + ar * HH + k0 + sk;
        *(short8*)&As[row * 40 + sk] = *(const short8*)src;
      } else {
        const float* src = Af + ar * HH + k0 + sk;
        float4 x = *(const float4*)src;
        float4 y = *(const float4*)(src + 4);
        short8 v;
        v[0] = (short)f2bf(x.x); v[1] = (short)f2bf(x.y);
        v[2] = (short)f2bf(x.z); v[3] = (short)f2bf(x.w);
        v[4] = (short)f2bf(y.x); v[5] = (short)f2bf(y.y);
        v[6] = (short)f2bf(y.z); v[7] = (short)f2bf(y.w);
        *(short8*)&As[row * 40 + sk] = v;
      }
      const unsigned short* wsrc = Wb + (size_t)(tn * 128 + row) * HH + k0 + sk;
      *(short8*)&Bs[row * 40 + sk] = *(const short8*)wsrc;
    }
    __syncthreads();
    short8 a[4], b[4];
#pragma unroll
    for (int i = 0; i < 4; ++i) a[i] = *(short8*)&As[(wr + i * 16 + l15) * 40 + l4 * 8];
#pragma unroll
    for (int j = 0; j < 4; ++j) b[j] = *(short8*)&Bs[(wc + j * 16 + l15) * 40 + l4 * 8];
#pragma unroll
    for (int i = 0; i < 4; ++i)
#pragma unroll
      for (int j = 0; j < 4; ++j)
        acc[i][j] = __builtin_amdgcn_mfma_f32_16x16x32_bf16(a[i], b[j], acc[i][j], 0, 0, 0);
  }
#pragma unroll
  for (int j = 0; j < 4; ++j) {
    const int gc = tn * 128 + wc + j * 16 + l15;
    const float bv = bias[gc];
#pragma unroll
    for (int i = 0; i < 4; ++i) {
#pragma unroll
      for (int jj = 0; jj < 4; ++jj) {
        const int gr = tm * 128 + wr + i * 16 + l4 * 4 + jj;
        const size_t orow = CPERM ? rowperm(gr) : (size_t)gr;
        const float val = acc[i][j][jj] + bv;
        if (OUTF16) ((_Float16*)GoutV)[orow * HH + gc] = (_Float16)val;
        else        ((float*)GoutV)[orow * HH + gc] = val;
      }
    }
  }
}

// Fused 2-layer recurrent kernel, diagonal pipeline. 64 WGs x 256 threads.
// Phase p: layer0 computes h0[p] = tanh(G[p] + h0[p-1]@Whh0^T)          (p < T)
//          layer1 computes h1[p-1] = tanh(h0[p-1]@Wih1^T + h1[p-2]@Whh1^T + b1)  (p >= 1)
// One grid barrier per phase (1024 barriers total, none after phase T).
// WG g owns output columns [g*16, g*16+16) for BOTH layers; wave wid owns rows
// [wid*16, wid*16+16). LDS holds Whh0 slice (32KB) + [Wih1;Whh1] slice (64KB).
__global__ __launch_bounds__(256)
void rec_fused(const unsigned short* __restrict__ Gh,   // [T][B][H] fp16 layer0 pre-act
               const unsigned short* __restrict__ Whh0_b,
               const unsigned short* __restrict__ Wih1_b,
               const unsigned short* __restrict__ Whh1_b,
               const float* __restrict__ bias1,
               unsigned short* __restrict__ h0p,        // [2][B*H] bf16
               unsigned short* __restrict__ h1p,        // [2][B*H] bf16
               float* __restrict__ outp,                // [B][T][H] fp32
               float* __restrict__ hT,                  // [2][B*H] fp32
               unsigned int* flags) {                   // 64 packed dwords
  const int g = blockIdx.x;
  const int tid = threadIdx.x, wid = tid >> 6, lane = tid & 63;
  const int l15 = lane & 15, l4 = lane >> 4, kp = l4 * 8;
  __shared__ unsigned short Wl0[16 * 1032];   // 33.0 KB
  __shared__ unsigned short Wl1[16 * 2056];   // 65.8 KB

  for (int idx = tid; idx < 16 * 64; idx += 256) {
    const int j = idx >> 6, kseg = (idx & 63) * 16;
    const short8* s0 = (const short8*)&Whh0_b[(size_t)(g * 16 + j) * HH + kseg];
    *(short8*)&Wl0[j * 1032 + kseg] = s0[0];
    *(short8*)&Wl0[j * 1032 + kseg + 8] = s0[1];
    const short8* s1 = (const short8*)&Wih1_b[(size_t)(g * 16 + j) * HH + kseg];
    *(short8*)&Wl1[j * 2056 + kseg] = s1[0];
    *(short8*)&Wl1[j * 2056 + kseg + 8] = s1[1];
    const short8* s2 = (const short8*)&Whh1_b[(size_t)(g * 16 + j) * HH + kseg];
    *(short8*)&Wl1[j * 2056 + 1024 + kseg] = s2[0];
    *(short8*)&Wl1[j * 2056 + 1024 + kseg + 8] = s2[1];
  }
  __syncthreads();

  const int col = g * 16 + l15;
  const unsigned short* b0row = &Wl0[l15 * 1032 + kp];
  const unsigned short* b1row = &Wl1[l15 * 2056 + kp];
  const float bc1 = bias1[col];
  const uint64_t myflag = (uint64_t)(flags + g);
  const uint64_t pollflag = (uint64_t)(flags + lane);

  int bidx[4];
#pragma unroll
  for (int jj = 0; jj < 4; ++jj) bidx[jj] = wid * 16 + l4 * 4 + jj;

  float gv[4], gn[4];
#pragma unroll
  for (int jj = 0; jj < 4; ++jj) gv[jj] = h2f(Gh[(size_t)bidx[jj] * HH + col]);

  for (int p = 0; p <= TT; ++p) {
    // prefetch next phase's G (immutable; overlaps with everything below)
    if (p + 1 < TT) {
#pragma unroll
      for (int jj = 0; jj < 4; ++jj)
        gn[jj] = h2f(Gh[((size_t)(p + 1) * BB + bidx[jj]) * HH + col]);
    }

    // ---- layer 0: h0[p] ----
    if (p < TT) {
      f32x4 acc0 = {}, acc1 = {};
      if (p > 0) {
        const unsigned short* arow =
            h0p + ((p - 1) & 1) * (BB * HH) + (size_t)(wid * 16 + l15) * HH + kp;
#pragma unroll
        for (int ks = 0; ks < 32; ks += 2) {
          short8 a0 = *(const short8*)(arow + ks * 32);
          short8 w0 = *(const short8*)(b0row + ks * 32);
          acc0 = __builtin_amdgcn_mfma_f32_16x16x32_bf16(a0, w0, acc0, 0, 0, 0);
          short8 a1 = *(const short8*)(arow + (ks + 1) * 32);
          short8 w1 = *(const short8*)(b0row + (ks + 1) * 32);
          acc1 = __builtin_amdgcn_mfma_f32_16x16x32_bf16(a1, w1, acc1, 0, 0, 0);
        }
      }
      unsigned short* hc = h0p + (p & 1) * (BB * HH);
#pragma unroll
      for (int jj = 0; jj < 4; ++jj) {
        const float pre = acc0[jj] + acc1[jj] + gv[jj];
        const float h = ftanh(pre);
        const unsigned short hb = f2bf(h);
        const uint64_t ha = (uint64_t)(hc + (size_t)bidx[jj] * HH + col);
        asm volatile("global_store_short %0, %1, off sc0 sc1"
                     :: "v"(ha), "v"((unsigned)hb) : "memory");
        if (p == TT - 1) hT[(size_t)bidx[jj] * HH + col] = h;
      }
    }

    // ---- layer 1: h1[p-1] ----
    if (p >= 1) {
      const int t1 = p - 1;
      f32x4 acc0 = {}, acc1 = {};
      {
        const unsigned short* arow =
            h0p + (t1 & 1) * (BB * HH) + (size_t)(wid * 16 + l15) * HH + kp;
#pragma unroll
        for (int ks = 0; ks < 32; ks += 2) {
          short8 a0 = *(const short8*)(arow + ks * 32);
          short8 w0 = *(const short8*)(b1row + ks * 32);
          acc0 = __builtin_amdgcn_mfma_f32_16x16x32_bf16(a0, w0, acc0, 0, 0, 0);
          short8 a1 = *(const short8*)(arow + (ks + 1) * 32);
          short8 w1 = *(const short8*)(b1row + (ks + 1) * 32);
          acc1 = __builtin_amdgcn_mfma_f32_16x16x32_bf16(a1, w1, acc1, 0, 0, 0);
        }
      }
      if (t1 > 0) {
        const unsigned short* arow =
            h1p + ((t1 - 1) & 1) * (BB * HH) + (size_t)(wid * 16 + l15) * HH + kp;
#pragma unroll
        for (int ks = 0; ks < 32; ks += 2) {
          short8 a0 = *(const short8*)(arow + ks * 32);
          short8 w0 = *(const short8*)(b1row + 1024 + ks * 32);
          acc0 = __builtin_amdgcn_mfma_f32_16x16x32_bf16(a0, w0, acc0, 0, 0, 0);
          short8 a1 = *(const short8*)(arow + (ks + 1) * 32);
          short8 w1 = *(const short8*)(b1row + 1024 + (ks + 1) * 32);
          acc1 = __builtin_amdgcn_mfma_f32_16x16x32_bf16(a1, w1, acc1, 0, 0, 0);
        }
      }
      unsigned short* hc = h1p + (t1 & 1) * (BB * HH);
#pragma unroll
      for (int jj = 0; jj < 4; ++jj) {
        const float pre = acc0[jj] + acc1[jj] + bc1;
        const float h = ftanh(pre);
        outp[((size_t)bidx[jj] * TT + t1) * HH + col] = h;
        if (t1 < TT - 1) {
          const unsigned short hb = f2bf(h);
          const uint64_t ha = (uint64_t)(hc + (size_t)bidx[jj] * HH + col);
          asm volatile("global_store_short %0, %1, off sc0 sc1"
                       :: "v"(ha), "v"((unsigned)hb) : "memory");
        } else {
          hT[BB * HH + (size_t)bidx[jj] * HH + col] = h;
        }
      }
    }

    // ---- grid barrier (skip after final phase) ----
    if (p < TT) {
      asm volatile("s_waitcnt vmcnt(0)" ::: "memory");   // drain WT h stores (per wave)
      __syncthreads();
      if (tid == 0) {
        const unsigned val = (unsigned)(p + 1);
        asm volatile("s_waitcnt vmcnt(0)\n\t"
                     "global_store_dword %0, %1, off sc0 sc1"
                     :: "v"(myflag), "v"(val) : "memory");
      }
      if (wid == 0) {
        const unsigned tgt = (unsigned)(p + 1);
        unsigned v;
        do {
          asm volatile("global_load_dword %0, %1, off sc0 sc1\n\t"
                       "s_waitcnt vmcnt(0)"
                       : "=v"(v) : "v"(pollflag) : "memory");
        } while (!__all((int)(v >= tgt)));
        __builtin_amdgcn_fence(__ATOMIC_ACQUIRE, "agent");  // buffer_inv, no writeback
      }
      __syncthreads();
#pragma unroll
      for (int jj = 0; jj < 4; ++jj) gv[jj] = gn[jj];
    }
  }
}

extern "C" void kernel_launch(void* const* d_in, const int* in_sizes, int n_in,
                              void* d_out, int out_size, void* d_ws, size_t ws_size,
                              hipStream_t stream) {
  const float* Xt  = (const float*)d_in[0];
  const float* Wih = (const float*)d_in[1];
  const float* bih = (const float*)d_in[2];
  const float* Whh = (const float*)d_in[3];
  const float* bhh = (const float*)d_in[4];
  float* out = (float*)d_out;                    // [B,T,H]
  float* hT  = out + (size_t)BB * TT * HH;       // [L,B,H]

  char* ws = (char*)d_ws;
  unsigned short* wih_b  = (unsigned short*)(ws);                  // 4 MB
  unsigned short* whh_b  = (unsigned short*)(ws + (4u << 20));     // 4 MB
  float*          bias01 = (float*)(ws + (8u << 20));              // 8 KB
  unsigned short* Gh     = (unsigned short*)(ws + (16u << 20));    // 128 MB fp16 [T][B][H]
  unsigned short* h0p    = (unsigned short*)(ws + (145u << 20));   // 256 KB
  unsigned short* h1p    = (unsigned short*)(ws + (146u << 20));   // 256 KB
  unsigned int*   flags  = (unsigned int*)(ws + (147u << 20));     // 4 KB

  if (ws_size < (150u << 20)) return;  // insufficient workspace -> loud validation failure

  hipMemsetAsync(flags, 0, 4096, stream);
  prep_kernel<<<8192, 256, 0, stream>>>(Wih, Whh, bih, bhh, wih_b, whh_b, bias01);

  // Phase A: Gh[t][b][:] = fp16( Xt[b][t][:] @ Wih0^T + (bih0+bhh0) )
  gemm_bias<false, true, false, true><<<4096, 256, 0, stream>>>(Xt, wih_b, bias01, Gh);

  // Phase B: fused 2-layer diagonal recurrence
  {
    const unsigned short* G = Gh;
    const unsigned short* W0 = whh_b;
    const unsigned short* W1i = wih_b + (size_t)HH * HH;
    const unsigned short* W1h = whh_b + (size_t)HH * HH;
    const float* b1 = bias01 + HH;
    unsigned short* p0 = h0p;
    unsigned short* p1 = h1p;
    float* op = out;
    float* ht = hT;
    unsigned int* fl = flags;
    void* args[] = {&G, &W0, &W1i, &W1h, &b1, &p0, &p1, &op, &ht, &fl};
    hipLaunchCooperativeKernel((void*)rec_fused, dim3(64), dim3(256), args, 0, stream);
  }
}

// Round 8
// 16087.047 us; speedup vs baseline: 1.0066x; 1.0066x over previous
//
#include <hip/hip_runtime.h>
#include <hip/hip_bf16.h>
#include <stdint.h>

#define HH 1024
#define BB 64
#define TT 1024

typedef __attribute__((ext_vector_type(8))) short short8;
typedef __attribute__((ext_vector_type(4))) float f32x4;

__device__ __forceinline__ unsigned short f2bf(float f) {
  union { float f; unsigned u; } v; v.f = f;
  unsigned r = v.u + 0x7fffu + ((v.u >> 16) & 1u);
  return (unsigned short)(r >> 16);
}

__device__ __forceinline__ float h2f(unsigned short u) {
  _Float16 h;
  __builtin_memcpy(&h, &u, 2);
  return (float)h;
}

// tanh(x) = 1 - 2/(exp(2x)+1)
__device__ __forceinline__ float ftanh(float x) {
  float e = __expf(2.0f * x);
  return 1.0f - 2.0f * __builtin_amdgcn_rcpf(e + 1.0f);
}

// Convert weights to bf16 (RNE) and fold the two biases together.
__global__ void prep_kernel(const float* __restrict__ Wih, const float* __restrict__ Whh,
                            const float* __restrict__ bih, const float* __restrict__ bhh,
                            unsigned short* __restrict__ wih_b, unsigned short* __restrict__ whh_b,
                            float* __restrict__ bias01) {
  int i = blockIdx.x * 256 + threadIdx.x;   // grid sized exactly 2*H*H
  wih_b[i] = f2bf(Wih[i]);
  whh_b[i] = f2bf(Whh[i]);
  if (i < 2 * HH) bias01[i] = bih[i] + bhh[i];
}

// Row permutation between [b][t] and [t][b] orderings.
__device__ __forceinline__ size_t rowperm(int r) {
  return ((size_t)(r & 63) << 10) | (size_t)(r >> 6);
}

// Bulk GEMM: Gout[crow(r), n] = sum_k A[arow(r),k] * W[n,k] + bias[n]. fp16 out.
template<bool ABF16, bool APERM, bool CPERM, bool OUTF16>
__global__ __launch_bounds__(256)
void gemm_bias(const void* __restrict__ Av, const unsigned short* __restrict__ Wb,
               const float* __restrict__ bias, void* __restrict__ GoutV) {
  __shared__ unsigned short As[128 * 40];
  __shared__ unsigned short Bs[128 * 40];
  const int tn = blockIdx.x & 7;
  const int tm = blockIdx.x >> 3;
  const int tid = threadIdx.x;
  const int wid = tid >> 6, lane = tid & 63;
  const int wr = (wid >> 1) * 64, wc = (wid & 1) * 64;
  const int l15 = lane & 15, l4 = lane >> 4;
  f32x4 acc[4][4] = {};

  const float* Af = (const float*)Av;
  const unsigned short* Ab = (const unsigned short*)Av;
  const int sr = tid >> 2;
  const int sk = (tid & 3) * 8;

  for (int k0 = 0; k0 < HH; k0 += 32) {
    __syncthreads();
#pragma unroll
    for (int p = 0; p < 2; ++p) {
      const int row = p * 64 + sr;
      const int rg = tm * 128 + row;
      const size_t ar = APERM ? rowperm(rg) : (size_t)rg;
      if (ABF16) {
        const unsigned short* src = Ab + ar * HH + k0 + sk;
        *(short8*)&As[row * 40 + sk] = *(const short8*)src;
      } else {
        const float* src = Af + ar * HH + k0 + sk;
        float4 x = *(const float4*)src;
        float4 y = *(const float4*)(src + 4);
        short8 v;
        v[0] = (short)f2bf(x.x); v[1] = (short)f2bf(x.y);
        v[2] = (short)f2bf(x.z); v[3] = (short)f2bf(x.w);
        v[4] = (short)f2bf(y.x); v[5] = (short)f2bf(y.y);
        v[6] = (short)f2bf(y.z); v[7] = (short)f2bf(y.w);
        *(short8*)&As[row * 40 + sk] = v;
      }
      const unsigned short* wsrc = Wb + (size_t)(tn * 128 + row) * HH + k0 + sk;
      *(short8*)&Bs[row * 40 + sk] = *(const short8*)wsrc;
    }
    __syncthreads();
    short8 a[4], b[4];
#pragma unroll
    for (int i = 0; i < 4; ++i) a[i] = *(short8*)&As[(wr + i * 16 + l15) * 40 + l4 * 8];
#pragma unroll
    for (int j = 0; j < 4; ++j) b[j] = *(short8*)&Bs[(wc + j * 16 + l15) * 40 + l4 * 8];
#pragma unroll
    for (int i = 0; i < 4; ++i)
#pragma unroll
      for (int j = 0; j < 4; ++j)
        acc[i][j] = __builtin_amdgcn_mfma_f32_16x16x32_bf16(a[i], b[j], acc[i][j], 0, 0, 0);
  }
#pragma unroll
  for (int j = 0; j < 4; ++j) {
    const int gc = tn * 128 + wc + j * 16 + l15;
    const float bv = bias[gc];
#pragma unroll
    for (int i = 0; i < 4; ++i) {
#pragma unroll
      for (int jj = 0; jj < 4; ++jj) {
        const int gr = tm * 128 + wr + i * 16 + l4 * 4 + jj;
        const size_t orow = CPERM ? rowperm(gr) : (size_t)gr;
        const float val = acc[i][j][jj] + bv;
        if (OUTF16) ((_Float16*)GoutV)[orow * HH + gc] = (_Float16)val;
        else        ((float*)GoutV)[orow * HH + gc] = val;
      }
    }
  }
}

// One diagonal phase of the fused 2-layer recurrence. 64 WGs x 256 threads.
// Launch p computes:  h0[p]   = tanh(G[p] + h0[p-1]@Whh0^T)                    (p < T)
//                     h1[p-1] = tanh(h0[p-1]@Wih1^T + h1[p-2]@Whh1^T + b1)     (p >= 1)
// Cross-step visibility comes from KERNEL LAUNCH BOUNDARIES (implicit
// release/acquire between dependent dispatches) — no fences, no flags, no
// cross-WG communication inside a launch. Correct by construction.
// WG g owns output columns [g*16, g*16+16); wave wid owns rows [wid*16,+16).
__global__ __launch_bounds__(256)
void step_kernel(int p,
                 const unsigned short* __restrict__ Gh,     // [T][B][H] fp16
                 const unsigned short* __restrict__ Whh0_b,
                 const unsigned short* __restrict__ Wih1_b,
                 const unsigned short* __restrict__ Whh1_b,
                 const float* __restrict__ bias1,
                 const unsigned short* __restrict__ h0_prev, // h0[p-1]
                 unsigned short* __restrict__ h0_cur,        // h0[p] (dest)
                 const unsigned short* __restrict__ h1_prev, // h1[p-2]
                 unsigned short* __restrict__ h1_cur,        // h1[p-1] (dest)
                 float* __restrict__ outp,                   // [B][T][H] fp32
                 float* __restrict__ hT) {                   // [2][B*H] fp32
  const int g = blockIdx.x;
  const int tid = threadIdx.x, wid = tid >> 6, lane = tid & 63;
  const int l15 = lane & 15, l4 = lane >> 4, kp = l4 * 8;
  __shared__ unsigned short Wl0[16 * 1032];   // 33.0 KB  Whh0 slice
  __shared__ unsigned short Wl1[16 * 2056];   // 65.8 KB  [Wih1 ; Whh1] slices

  for (int idx = tid; idx < 16 * 64; idx += 256) {
    const int j = idx >> 6, kseg = (idx & 63) * 16;
    if (p < TT) {
      const short8* s0 = (const short8*)&Whh0_b[(size_t)(g * 16 + j) * HH + kseg];
      *(short8*)&Wl0[j * 1032 + kseg] = s0[0];
      *(short8*)&Wl0[j * 1032 + kseg + 8] = s0[1];
    }
    if (p >= 1) {
      const short8* s1 = (const short8*)&Wih1_b[(size_t)(g * 16 + j) * HH + kseg];
      *(short8*)&Wl1[j * 2056 + kseg] = s1[0];
      *(short8*)&Wl1[j * 2056 + kseg + 8] = s1[1];
      if (p >= 2) {
        const short8* s2 = (const short8*)&Whh1_b[(size_t)(g * 16 + j) * HH + kseg];
        *(short8*)&Wl1[j * 2056 + 1024 + kseg] = s2[0];
        *(short8*)&Wl1[j * 2056 + 1024 + kseg + 8] = s2[1];
      }
    }
  }
  __syncthreads();

  const int col = g * 16 + l15;
  const unsigned short* b0row = &Wl0[l15 * 1032 + kp];
  const unsigned short* b1row = &Wl1[l15 * 2056 + kp];
  const size_t arow_half = (size_t)(wid * 16 + l15) * HH + kp;

  int bidx[4];
#pragma unroll
  for (int jj = 0; jj < 4; ++jj) bidx[jj] = wid * 16 + l4 * 4 + jj;

  // ---- merged chain: one h0[p-1] load feeds Whh0 (layer0) + Wih1 (layer1) ----
  f32x4 c00 = {}, c01 = {}, cI0 = {}, cI1 = {};
  if (p >= 1) {
    const unsigned short* arow = h0_prev + arow_half;
#pragma unroll
    for (int ks = 0; ks < 32; ks += 2) {
      short8 a0 = *(const short8*)(arow + ks * 32);
      short8 a1 = *(const short8*)(arow + (ks + 1) * 32);
      short8 wI0 = *(const short8*)(b1row + ks * 32);
      short8 wI1 = *(const short8*)(b1row + (ks + 1) * 32);
      cI0 = __builtin_amdgcn_mfma_f32_16x16x32_bf16(a0, wI0, cI0, 0, 0, 0);
      cI1 = __builtin_amdgcn_mfma_f32_16x16x32_bf16(a1, wI1, cI1, 0, 0, 0);
      if (p < TT) {
        short8 w00 = *(const short8*)(b0row + ks * 32);
        short8 w01 = *(const short8*)(b0row + (ks + 1) * 32);
        c00 = __builtin_amdgcn_mfma_f32_16x16x32_bf16(a0, w00, c00, 0, 0, 0);
        c01 = __builtin_amdgcn_mfma_f32_16x16x32_bf16(a1, w01, c01, 0, 0, 0);
      }
    }
  }

  // ---- finalize h0[p] ----
  if (p < TT) {
#pragma unroll
    for (int jj = 0; jj < 4; ++jj) {
      const float gvv = h2f(Gh[((size_t)p * BB + bidx[jj]) * HH + col]);
      const float pre = c00[jj] + c01[jj] + gvv;
      const float h = ftanh(pre);
      h0_cur[(size_t)bidx[jj] * HH + col] = f2bf(h);
      if (p == TT - 1) hT[(size_t)bidx[jj] * HH + col] = h;
    }
  }

  // ---- layer 1: Whh1 chain over h1[p-2]; finalize h1[p-1] ----
  if (p >= 1) {
    const int t1 = p - 1;
    f32x4 cH0 = {}, cH1 = {};
    if (t1 > 0) {
      const unsigned short* arow = h1_prev + arow_half;
#pragma unroll
      for (int ks = 0; ks < 32; ks += 2) {
        short8 a0 = *(const short8*)(arow + ks * 32);
        short8 wH0 = *(const short8*)(b1row + 1024 + ks * 32);
        cH0 = __builtin_amdgcn_mfma_f32_16x16x32_bf16(a0, wH0, cH0, 0, 0, 0);
        short8 a1 = *(const short8*)(arow + (ks + 1) * 32);
        short8 wH1 = *(const short8*)(b1row + 1024 + (ks + 1) * 32);
        cH1 = __builtin_amdgcn_mfma_f32_16x16x32_bf16(a1, wH1, cH1, 0, 0, 0);
      }
    }
    const float bc1 = bias1[col];
#pragma unroll
    for (int jj = 0; jj < 4; ++jj) {
      const float pre = cI0[jj] + cI1[jj] + cH0[jj] + cH1[jj] + bc1;
      const float h = ftanh(pre);
      outp[((size_t)bidx[jj] * TT + t1) * HH + col] = h;
      if (t1 < TT - 1) h1_cur[(size_t)bidx[jj] * HH + col] = f2bf(h);
      else             hT[BB * HH + (size_t)bidx[jj] * HH + col] = h;
    }
  }
}

extern "C" void kernel_launch(void* const* d_in, const int* in_sizes, int n_in,
                              void* d_out, int out_size, void* d_ws, size_t ws_size,
                              hipStream_t stream) {
  const float* Xt  = (const float*)d_in[0];
  const float* Wih = (const float*)d_in[1];
  const float* bih = (const float*)d_in[2];
  const float* Whh = (const float*)d_in[3];
  const float* bhh = (const float*)d_in[4];
  float* out = (float*)d_out;                    // [B,T,H]
  float* hT  = out + (size_t)BB * TT * HH;       // [L,B,H]

  char* ws = (char*)d_ws;
  unsigned short* wih_b  = (unsigned short*)(ws);                  // 4 MB
  unsigned short* whh_b  = (unsigned short*)(ws + (4u << 20));     // 4 MB
  float*          bias01 = (float*)(ws + (8u << 20));              // 8 KB
  unsigned short* Gh     = (unsigned short*)(ws + (16u << 20));    // 128 MB fp16 [T][B][H]
  unsigned short* h0p    = (unsigned short*)(ws + (145u << 20));   // 256 KB [2][B*H]
  unsigned short* h1p    = (unsigned short*)(ws + (146u << 20));   // 256 KB [2][B*H]

  if (ws_size < (150u << 20)) return;  // insufficient workspace -> loud validation failure

  prep_kernel<<<8192, 256, 0, stream>>>(Wih, Whh, bih, bhh, wih_b, whh_b, bias01);

  // Phase A: Gh[t][b][:] = fp16( Xt[b][t][:] @ Wih0^T + (bih0+bhh0) )
  gemm_bias<false, true, false, true><<<4096, 256, 0, stream>>>(Xt, wih_b, bias01, Gh);

  // Phase B: 1025 diagonal-phase launches; kernel boundaries provide coherence.
  const unsigned short* W1i = wih_b + (size_t)HH * HH;
  const unsigned short* W1h = whh_b + (size_t)HH * HH;
  const float* b1 = bias01 + HH;
  const size_t BH = (size_t)BB * HH;
  for (int p = 0; p <= TT; ++p) {
    unsigned short* h0_prev = h0p + ((size_t)((p + 1) & 1)) * BH;
    unsigned short* h0_cur  = h0p + ((size_t)(p & 1)) * BH;
    unsigned short* h1_prev = h1p + ((size_t)(p & 1)) * BH;        // holds h1[p-2]
    unsigned short* h1_cur  = h1p + ((size_t)((p + 1) & 1)) * BH;  // dest for h1[p-1]
    step_kernel<<<64, 256, 0, stream>>>(p, Gh, whh_b, W1i, W1h, b1,
                                        h0_prev, h0_cur, h1_prev, h1_cur, out, hT);
  }
}